// Round 3
// baseline (1867.552 us; speedup 1.0000x reference)
//
#include <hip/hip_runtime.h>

typedef unsigned short u16;
typedef unsigned int u32;
typedef __bf16 bf16x8 __attribute__((ext_vector_type(8)));
typedef float f32x4 __attribute__((ext_vector_type(4)));

union FragU { uint4 u; bf16x8 v; };

__device__ __forceinline__ u16 f2bf(float f) {
  union { float f; u32 u; } c; c.f = f;
  u32 u = c.u;
  return (u16)((u + 0x7fffu + ((u >> 16) & 1u)) >> 16);
}

__device__ __forceinline__ bf16x8 ldfrag(const u16* p) {
  FragU t; t.u = *(const uint4*)p; return t.v;
}

// Device-coherent (bypass L1/L2, served at L3/MALL) tagged-state primitives.
// State element = (step_tag << 16) | bf16(h). Single-hop sync: producers
// fire-and-forget tagged stores; consumers poll data words directly until
// all tags match the expected step. No flags, no drains, no fences.
__device__ __forceinline__ void st_u32_coh(u32* p, u32 v) {
  asm volatile("global_store_dword %0, %1, off sc0 sc1" :: "v"(p), "v"(v) : "memory");
}

// ---------------------------------------------------------------------------
// Sizes
//   d_out: h1s [0, 52428800) | h2s [52428800, 78643200) | outputs [78643200, 104857600)
//   h0 fp32 staging reuses the outputs region (overwritten later by out_kernel).
//   ws: wcat(bf16 1536x1536) | wh(bf16 1536x512) | woutb(bf16 512x1536) |
//       bcat(f32 1536) | win2(f32 1536x2) | state(u32 2x256x1536) | bar(1024 int, unused)
// ---------------------------------------------------------------------------

__global__ void pack_kernel(const float* __restrict__ Wrec1, const float* __restrict__ Wrec2,
                            const float* __restrict__ W12,   const float* __restrict__ W21,
                            const float* __restrict__ Wh1,   const float* __restrict__ Wh2,
                            const float* __restrict__ Wout,
                            const float* __restrict__ bin1,  const float* __restrict__ bin2,
                            const float* __restrict__ brec1, const float* __restrict__ brec2,
                            const float* __restrict__ b12,   const float* __restrict__ b21,
                            const float* __restrict__ Win1,  const float* __restrict__ Win2,
                            u16* __restrict__ wcat, u16* __restrict__ wh, u16* __restrict__ woutb,
                            float* __restrict__ bcat, float* __restrict__ win2, int* __restrict__ bar)
{
  int i = blockIdx.x * 256 + threadIdx.x;
  if (i < 2359296) {               // W_cat[n][k]: row n = output neuron, k over [h1|h2]
    int n = i / 1536, k = i - n * 1536;
    float v;
    if (n < 1024) v = (k < 1024) ? Wrec1[n * 1024 + k] : W21[n * 512 + (k - 1024)];
    else { int n2 = n - 1024; v = (k < 1024) ? W12[n2 * 1024 + k] : Wrec2[n2 * 512 + (k - 1024)]; }
    wcat[i] = f2bf(v);
    return;
  }
  i -= 2359296;
  if (i < 786432) {                // Wh[n][o]
    int n = i >> 9, k = i & 511;
    wh[i] = f2bf(n < 1024 ? Wh1[n * 512 + k] : Wh2[(n - 1024) * 512 + k]);
    return;
  }
  i -= 786432;
  if (i < 786432) { woutb[i] = f2bf(Wout[i]); return; }
  i -= 786432;
  if (i < 1536) {                  // combined bias: b_in + b_rec + b_cross
    bcat[i] = (i < 1024) ? (bin1[i] + brec1[i] + b21[i])
                         : (bin2[i - 1024] + brec2[i - 1024] + b12[i - 1024]);
    return;
  }
  i -= 1536;
  if (i < 3072) {                  // input-projection coeffs
    int n = i >> 1, c = i & 1;
    win2[i] = (n < 1024) ? Win1[n * 2 + c] : Win2[(n - 1024) * 2 + c];
    return;
  }
  i -= 3072;
  if (i < 1024) bar[i] = 0;        // legacy barrier area (unused; ws is poisoned)
}

// ---------------------------------------------------------------------------
// h0 = pc0 @ [Wh1|Wh2]^T   (M=256, N=1536, K=512)
// Writes fp32 h0 (into outputs region of d_out) + tagged u32 state buf0 (tag=1)
// + zeroes state buf1 (tag 0 != any expected tag; kills workspace poison).
// State init uses device-coherent stores so the tagged buffers never depend on
// the end-of-dispatch L2 writeback (pollers read them with sc0 sc1 loads).
// grid 96 = 4 mt x 24 nt, block 256 (4 waves, each 32x32 quadrant of 64x64 tile)
// ---------------------------------------------------------------------------
__global__ __launch_bounds__(256) void h0_kernel(const float* __restrict__ pc0,
                                                 const u16* __restrict__ wh,
                                                 float* __restrict__ h0scr, u32* __restrict__ st)
{
  __shared__ u16 As[64 * 32];
  __shared__ u16 Bs[64 * 32];
  int tid = threadIdx.x;
  int lane = tid & 63, w = tid >> 6;
  int q = lane >> 4, col = lane & 15;
  int mt = blockIdx.x & 3, nt = blockIdx.x >> 2;
  int wm = w & 1, wn = w >> 1;
  f32x4 zero = {0.f, 0.f, 0.f, 0.f};
  f32x4 acc[2][2];
#pragma unroll
  for (int a = 0; a < 2; ++a)
#pragma unroll
    for (int b = 0; b < 2; ++b) acc[a][b] = zero;

  for (int k0 = 0; k0 < 512; k0 += 32) {
    __syncthreads();
#pragma unroll
    for (int it = 0; it < 2; ++it) {         // A: 64x32 fp32 -> bf16 LDS
      int f = tid + 256 * it; int r = f >> 3, c4 = f & 7;
      float4 v = *(const float4*)(pc0 + (mt * 64 + r) * 512 + k0 + c4 * 4);
      u16* d = &As[r * 32 + c4 * 4];
      d[0] = f2bf(v.x); d[1] = f2bf(v.y); d[2] = f2bf(v.z); d[3] = f2bf(v.w);
    }
    {                                        // B: 64x32 bf16
      int r = tid >> 2, c8 = tid & 3;
      *(uint4*)&Bs[r * 32 + c8 * 8] = *(const uint4*)(wh + (nt * 64 + r) * 512 + k0 + c8 * 8);
    }
    __syncthreads();
    bf16x8 af[2], bfr[2];
#pragma unroll
    for (int mi = 0; mi < 2; ++mi) af[mi] = ldfrag(&As[(wm * 32 + mi * 16 + col) * 32 + q * 8]);
#pragma unroll
    for (int ni = 0; ni < 2; ++ni) bfr[ni] = ldfrag(&Bs[(wn * 32 + ni * 16 + col) * 32 + q * 8]);
#pragma unroll
    for (int mi = 0; mi < 2; ++mi)
#pragma unroll
      for (int ni = 0; ni < 2; ++ni)
        acc[mi][ni] = __builtin_amdgcn_mfma_f32_16x16x32_bf16(af[mi], bfr[ni], acc[mi][ni], 0, 0, 0);
  }
#pragma unroll
  for (int mi = 0; mi < 2; ++mi)
#pragma unroll
    for (int ni = 0; ni < 2; ++ni)
#pragma unroll
      for (int v = 0; v < 4; ++v) {
        int m = mt * 64 + wm * 32 + mi * 16 + q * 4 + v;
        int n = nt * 64 + wn * 32 + ni * 16 + col;
        float val = acc[mi][ni][v];
        h0scr[m * 1536 + n] = val;
        st_u32_coh(&st[m * 1536 + n], (u32)f2bf(val) | 0x10000u);   // buf0, tag 1
        st_u32_coh(&st[393216 + m * 1536 + n], 0u);                 // buf1, tag 0
      }
}

// ---------------------------------------------------------------------------
// Persistent recurrent kernel, tagged-state single-hop sync.
// 256 blocks x 512 thr (1 block/CU). Block = (mb = 16 batch rows, nb = 96 neurons).
// W register-stationary: wave w holds 96n x 192k slice as 36 B-fragments.
// Per step: poll 12x dwordx4 tagged A-words until all 48 tags == t+1 ->
// unpack (v_perm) -> 36 MFMA -> LDS K-reduction -> tanh update ->
// fire-and-forget tagged state store (tag t+2). No flags, no drains, no fences.
// Safety: a buffer is only overwritten with tag g after every group member
// published g-1, which implies they consumed g-2 from that buffer.
// ---------------------------------------------------------------------------
__global__ __launch_bounds__(512, 1) void rnn_kernel(
    const u16* __restrict__ wcat, const float* __restrict__ bcat, const float* __restrict__ win2,
    const float* __restrict__ x, const float* __restrict__ h0scr,
    u32* __restrict__ state, float* __restrict__ out)
{
  __shared__ float P[12800];                 // 8 waves x 16 rows x (96+pad4) partials
  int tid = threadIdx.x;
  int lane = tid & 63, w = tid >> 6;
  int q = lane >> 4, col = lane & 15;
  int mb = blockIdx.x & 15, nb = blockIdx.x >> 4;   // group (same mb) stays on one XCD

  bf16x8 wf[6][6];                           // persistent weight fragments
  {
    const u16* wp = wcat + (nb * 96 + col) * 1536 + w * 192 + q * 8;
#pragma unroll
    for (int ni = 0; ni < 6; ++ni)
#pragma unroll
      for (int kc = 0; kc < 6; ++kc)
        wf[ni][kc] = ldfrag(wp + ni * (16 * 1536) + kc * 32);
  }

  // per-lane epilogue constants: 3 state elements per lane (16x96 over 512 threads)
  int poff[3], hoff[3], ooff[3], rs[3];
  float bias_[3], wi0_[3], wi1_[3], cm_[3], ca_[3], hreg[3];
  const float* xp_[3];
#pragma unroll
  for (int e = 0; e < 3; ++e) {
    int idx = e * 64 + lane;
    int r = w * 2 + idx / 96;                // block-local row 0..15
    int c = idx - (idx / 96) * 96;           // 0..95
    int ng = nb * 96 + c;                    // global neuron
    int b = mb * 16 + r;                     // global batch row
    poff[e] = r * 100 + c;
    hoff[e] = b * 1536 + ng;
    bias_[e] = bcat[ng];
    wi0_[e] = win2[2 * ng]; wi1_[e] = win2[2 * ng + 1];
    float al = (ng < 1024) ? 0.1f : 0.05f;
    ca_[e] = al; cm_[e] = 1.f - al;
    ooff[e] = (ng < 1024) ? (b * 204800 + ng) : (52428800 + b * 102400 + (ng - 1024));
    rs[e] = (ng < 1024) ? 1024 : 512;
    xp_[e] = x + b * 400;
    hreg[e] = h0scr[hoff[e]];
  }

  int aoff = (mb * 16 + col) * 1536 + w * 192 + q * 8;   // u32 elements

  for (int t = 0; t < 200; ++t) {
    const u32* hr = state + ((t & 1) ? 393216 : 0) + aoff;
    u32 es = (u32)(t + 1) << 16;             // expected tag this step

    uint4 r0, r1, r2, r3, r4, r5, r6, r7, r8, r9, r10, r11;
    for (;;) {
      asm volatile(
          "global_load_dwordx4 %0, %12, off sc0 sc1\n\t"
          "global_load_dwordx4 %1, %12, off offset:16 sc0 sc1\n\t"
          "global_load_dwordx4 %2, %12, off offset:128 sc0 sc1\n\t"
          "global_load_dwordx4 %3, %12, off offset:144 sc0 sc1\n\t"
          "global_load_dwordx4 %4, %12, off offset:256 sc0 sc1\n\t"
          "global_load_dwordx4 %5, %12, off offset:272 sc0 sc1\n\t"
          "global_load_dwordx4 %6, %12, off offset:384 sc0 sc1\n\t"
          "global_load_dwordx4 %7, %12, off offset:400 sc0 sc1\n\t"
          "global_load_dwordx4 %8, %12, off offset:512 sc0 sc1\n\t"
          "global_load_dwordx4 %9, %12, off offset:528 sc0 sc1\n\t"
          "global_load_dwordx4 %10, %12, off offset:640 sc0 sc1\n\t"
          "global_load_dwordx4 %11, %12, off offset:656 sc0 sc1\n\t"
          "s_waitcnt vmcnt(0)"
          : "=&v"(r0), "=&v"(r1), "=&v"(r2), "=&v"(r3), "=&v"(r4), "=&v"(r5),
            "=&v"(r6), "=&v"(r7), "=&v"(r8), "=&v"(r9), "=&v"(r10), "=&v"(r11)
          : "v"(hr)
          : "memory");
      u32 acc = 0;
#define TCHK(rr) acc |= (rr.x ^ es); acc |= (rr.y ^ es); acc |= (rr.z ^ es); acc |= (rr.w ^ es)
      TCHK(r0); TCHK(r1); TCHK(r2); TCHK(r3); TCHK(r4); TCHK(r5);
      TCHK(r6); TCHK(r7); TCHK(r8); TCHK(r9); TCHK(r10); TCHK(r11);
#undef TCHK
      if (__all((int)((acc >> 16) == 0))) break;
      __builtin_amdgcn_s_sleep(1);           // backoff: cap poll L3 traffic
    }

    if (t > 0) {                             // deferred fp32 history write for t-1
#pragma unroll
      for (int e = 0; e < 3; ++e) out[ooff[e] + (t - 1) * rs[e]] = hreg[e];
    }

    bf16x8 af[6];
#define UNPK(dst, a, b) { FragU f_;                                       \
      f_.u.x = __builtin_amdgcn_perm(a.y, a.x, 0x05040100u);              \
      f_.u.y = __builtin_amdgcn_perm(a.w, a.z, 0x05040100u);              \
      f_.u.z = __builtin_amdgcn_perm(b.y, b.x, 0x05040100u);              \
      f_.u.w = __builtin_amdgcn_perm(b.w, b.z, 0x05040100u);              \
      dst = f_.v; }
    UNPK(af[0], r0, r1); UNPK(af[1], r2, r3); UNPK(af[2], r4, r5);
    UNPK(af[3], r6, r7); UNPK(af[4], r8, r9); UNPK(af[5], r10, r11);
#undef UNPK

    f32x4 zero = {0.f, 0.f, 0.f, 0.f};
    f32x4 acc[6];
#pragma unroll
    for (int ni = 0; ni < 6; ++ni) acc[ni] = zero;
#pragma unroll
    for (int kc = 0; kc < 6; ++kc)
#pragma unroll
      for (int ni = 0; ni < 6; ++ni)
        acc[ni] = __builtin_amdgcn_mfma_f32_16x16x32_bf16(af[kc], wf[ni][kc], acc[ni], 0, 0, 0);
#pragma unroll
    for (int ni = 0; ni < 6; ++ni)
#pragma unroll
      for (int v = 0; v < 4; ++v)
        P[(w * 16 + q * 4 + v) * 100 + ni * 16 + col] = acc[ni][v];
    __syncthreads();

    u32* hw = state + ((t & 1) ? 0 : 393216);
    u32 wtag = (u32)(t + 2) << 16;
#pragma unroll
    for (int e = 0; e < 3; ++e) {
      float s = 0.f;
#pragma unroll
      for (int p = 0; p < 8; ++p) s += P[p * 1600 + poff[e]];
      float2 xv = *(const float2*)(xp_[e] + 2 * t);
      float tt = s + bias_[e] + xv.x * wi0_[e] + xv.y * wi1_[e];
      float th = tanhf(tt);
      hreg[e] = cm_[e] * hreg[e] + ca_[e] * th;
      st_u32_coh(&hw[hoff[e]], (u32)f2bf(hreg[e]) | wtag);   // fire-and-forget
    }
    __syncthreads();                         // protect P for next iteration
  }
#pragma unroll
  for (int e = 0; e < 3; ++e) out[ooff[e] + 199 * rs[e]] = hreg[e];
}

// ---------------------------------------------------------------------------
// outputs = [h1s|h2s] @ W_out^T   (M=51200, N=512, K=1536)
// 800 blocks, tile 64(m) x 512(n, full): W_out stays L2-resident, A streamed once.
// ---------------------------------------------------------------------------
__global__ __launch_bounds__(256, 2) void out_kernel(const float* __restrict__ h1s,
                                                     const float* __restrict__ h2s,
                                                     const u16* __restrict__ woutb,
                                                     float* __restrict__ outp)
{
  __shared__ u16 As[64 * 32];
  __shared__ u16 Bs[512 * 32];
  int tid = threadIdx.x;
  int lane = tid & 63, w = tid >> 6;
  int q = lane >> 4, col = lane & 15;
  int mt = blockIdx.x;
  f32x4 zero = {0.f, 0.f, 0.f, 0.f};
  f32x4 acc[4][8];
#pragma unroll
  for (int a = 0; a < 4; ++a)
#pragma unroll
    for (int b = 0; b < 8; ++b) acc[a][b] = zero;

  for (int k0 = 0; k0 < 1536; k0 += 32) {
    __syncthreads();
    const float* Asrc; int lda;
    if (k0 < 1024) { Asrc = h1s + k0; lda = 1024; }
    else           { Asrc = h2s + (k0 - 1024); lda = 512; }
#pragma unroll
    for (int it = 0; it < 2; ++it) {         // A: 64x32 fp32 -> bf16
      int f = tid + 256 * it; int r = f >> 3, c4 = f & 7;
      float4 v = *(const float4*)(Asrc + (mt * 64 + r) * lda + c4 * 4);
      u16* d = &As[r * 32 + c4 * 4];
      d[0] = f2bf(v.x); d[1] = f2bf(v.y); d[2] = f2bf(v.z); d[3] = f2bf(v.w);
    }
#pragma unroll
    for (int it = 0; it < 8; ++it) {         // B: 512x32 bf16
      int f = tid + 256 * it; int r = f >> 2, c8 = f & 3;
      *(uint4*)&Bs[r * 32 + c8 * 8] = *(const uint4*)(woutb + r * 1536 + k0 + c8 * 8);
    }
    __syncthreads();
    bf16x8 af[4], bfr[8];
#pragma unroll
    for (int mi = 0; mi < 4; ++mi) af[mi] = ldfrag(&As[(mi * 16 + col) * 32 + q * 8]);
#pragma unroll
    for (int ni = 0; ni < 8; ++ni) bfr[ni] = ldfrag(&Bs[(w * 128 + ni * 16 + col) * 32 + q * 8]);
#pragma unroll
    for (int mi = 0; mi < 4; ++mi)
#pragma unroll
      for (int ni = 0; ni < 8; ++ni)
        acc[mi][ni] = __builtin_amdgcn_mfma_f32_16x16x32_bf16(af[mi], bfr[ni], acc[mi][ni], 0, 0, 0);
  }
#pragma unroll
  for (int mi = 0; mi < 4; ++mi)
#pragma unroll
    for (int ni = 0; ni < 8; ++ni)
#pragma unroll
      for (int v = 0; v < 4; ++v)
        outp[(mt * 64 + mi * 16 + q * 4 + v) * 512 + w * 128 + ni * 16 + col] = acc[mi][ni][v];
}

extern "C" void kernel_launch(void* const* d_in, const int* in_sizes, int n_in,
                              void* d_out, int out_size, void* d_ws, size_t ws_size,
                              hipStream_t stream) {
  const float* inputs = (const float*)d_in[0];
  const float* pc0   = (const float*)d_in[1];
  const float* Win1  = (const float*)d_in[2];
  const float* bin1  = (const float*)d_in[3];
  const float* Win2  = (const float*)d_in[4];
  const float* bin2  = (const float*)d_in[5];
  const float* Wrec1 = (const float*)d_in[6];
  const float* brec1 = (const float*)d_in[7];
  const float* Wrec2 = (const float*)d_in[8];
  const float* brec2 = (const float*)d_in[9];
  const float* W12   = (const float*)d_in[10];
  const float* b12   = (const float*)d_in[11];
  const float* W21   = (const float*)d_in[12];
  const float* b21   = (const float*)d_in[13];
  const float* Wout  = (const float*)d_in[14];
  const float* Wh1   = (const float*)d_in[15];
  const float* Wh2   = (const float*)d_in[16];

  char* ws = (char*)d_ws;
  u16*   wcat  = (u16*)(ws + 0);
  u16*   wh    = (u16*)(ws + 4718592);
  u16*   woutb = (u16*)(ws + 6291456);
  float* bcat  = (float*)(ws + 7864320);
  float* win2  = (float*)(ws + 7870464);
  u32*   state = (u32*)(ws + 7882752);       // 2 x 256 x 1536 u32 = 3 MB
  int*   bar   = (int*)(ws + 11028480);      // legacy, zeroed by pack, unused

  float* out = (float*)d_out;
  float* h0scr = out + 19660800;             // fp32 h0 staging inside outputs region

  pack_kernel<<<15382, 256, 0, stream>>>(Wrec1, Wrec2, W12, W21, Wh1, Wh2, Wout,
                                         bin1, bin2, brec1, brec2, b12, b21, Win1, Win2,
                                         wcat, wh, woutb, bcat, win2, bar);
  h0_kernel<<<96, 256, 0, stream>>>(pc0, wh, h0scr, state);
  rnn_kernel<<<256, 512, 0, stream>>>(wcat, bcat, win2, inputs, h0scr, state, out);
  out_kernel<<<800, 256, 0, stream>>>(out, out + 52428800, woutb, out + 78643200);
}